// Round 1
// 430.302 us; speedup vs baseline: 1.0078x; 1.0078x over previous
//
#include <hip/hip_runtime.h>
#include <hip/hip_bf16.h>

// Problem constants (from reference): B=8, T=128, U=64, V=1024, blank=V-1.
#define BB 8
#define TT 128
#define UU 64
#define VV 1024
#define U1 65                      // U+1
#define NROWS (BB * TT * U1)       // 66560 log-softmax rows
#define NDIAG (TT + UU)            // 192 anti-diagonals
#define DSZ (NDIAG * U1)           // 12480 float2 slots per batch (diag-major)

__device__ __forceinline__ float wave_max64(float v) {
#pragma unroll
    for (int off = 32; off; off >>= 1) v = fmaxf(v, __shfl_xor(v, off, 64));
    return v;
}
__device__ __forceinline__ float wave_sum64(float v) {
#pragma unroll
    for (int off = 32; off; off >>= 1) v += __shfl_xor(v, off, 64);
    return v;
}

// Kernel 1: one wave per (b,t,u) row of V=1024 logits. Computes logsumexp,
// then extracts the two surviving log-probs (blank=last class, target) from
// the already-loaded registers via shuffles, and writes ONE float2 into the
// diagonal-major slab P[b][(t+u)*U1 + u] = {lp_blank, lp_emit}.
__global__ __launch_bounds__(256) void rnnt_lse_kernel(
    const float* __restrict__ logits, const int* __restrict__ targets,
    float2* __restrict__ P) {
    const int wave = threadIdx.x >> 6;
    const int lane = threadIdx.x & 63;
    const int row  = blockIdx.x * 4 + wave;          // grid*4 == NROWS exactly
    const float4* p4 = (const float4*)(logits + (size_t)row * VV);

    float4 x0 = p4[lane];
    float4 x1 = p4[lane + 64];
    float4 x2 = p4[lane + 128];
    float4 x3 = p4[lane + 192];

    float m = fmaxf(fmaxf(fmaxf(x0.x, x0.y), fmaxf(x0.z, x0.w)),
                    fmaxf(fmaxf(x1.x, x1.y), fmaxf(x1.z, x1.w)));
    m = fmaxf(m, fmaxf(fmaxf(fmaxf(x2.x, x2.y), fmaxf(x2.z, x2.w)),
                       fmaxf(fmaxf(x3.x, x3.y), fmaxf(x3.z, x3.w))));
    m = wave_max64(m);

    float s = __expf(x0.x - m) + __expf(x0.y - m) + __expf(x0.z - m) + __expf(x0.w - m)
            + __expf(x1.x - m) + __expf(x1.y - m) + __expf(x1.z - m) + __expf(x1.w - m)
            + __expf(x2.x - m) + __expf(x2.y - m) + __expf(x2.z - m) + __expf(x2.w - m)
            + __expf(x3.x - m) + __expf(x3.y - m) + __expf(x3.z - m) + __expf(x3.w - m);
    s = wave_sum64(s);
    const float lse = m + __logf(s);                 // all lanes hold it

    const int b   = row / (TT * U1);
    const int rem = row - b * (TT * U1);
    const int t   = rem / U1;
    const int u   = rem - t * U1;

    // blank logit = element 1023 = x3.w of lane 63
    const float blankv = __shfl(x3.w, 63, 64) - lse;
    float emitv = 0.f;
    if (u < UU) {                                    // wave-uniform branch
        const int tgt = targets[b * UU + u];         // wave-uniform scalar
        const int q = tgt >> 2, grp = q >> 6, sl = q & 63, c = tgt & 3;
        float4 g4 = (grp == 0) ? x0 : (grp == 1) ? x1 : (grp == 2) ? x2 : x3;
        float cv = (c == 0) ? g4.x : (c == 1) ? g4.y : (c == 2) ? g4.z : g4.w;
        emitv = __shfl(cv, sl, 64) - lse;
    }
    if (lane == 0) P[(size_t)b * DSZ + (t + u) * U1 + u] = make_float2(blankv, emitv);
}

// Kernel 2: anti-diagonal wavefront DP, ONE wave per batch, barrier-free,
// NO LDS. Lane l owns column u=l; lane 63 also owns u=64. alpha diagonal
// lives in registers (neighbor via __shfl_up). The diag-major P layout makes
// each diagonal's {blank,emit} row a naturally coalesced 512 B float2 load,
// so we read it straight into a 16-deep rotating register prefetch pipeline
// (statically indexed via full unroll) — ~1000 cycles of latency tolerance,
// enough for an HBM miss, with zero LDS round-trip on the serial chain.
#define PF 16                      // prefetch depth; NDIAG/PF = 12 exactly
__global__ __launch_bounds__(64) void rnnt_dp_kernel(
    const float2* __restrict__ P, const int* __restrict__ logit_lengths,
    const int* __restrict__ target_lengths, float* __restrict__ out) {
    const int b = blockIdx.x;
    const int l = threadIdx.x;                       // 0..63
    const float2* Pg = P + (size_t)b * DSZ;
    const float*  Pf = (const float*)Pg;
    const int tl = logit_lengths[b] - 1;             // in [63,127]
    const int ul = target_lengths[b];                // in [32,64]

    const float NEG = -1e30f;
    float aprev   = (l == 0) ? 0.f : NEG;            // diag 0: alpha[0][0]=0
    float aprev64 = NEG;                             // lane63's u=64 cell
    float res = 0.f;

    float2 prb[PF];                                  // {blank(c,l), emit(c,l)}
    float  p64b[PF];                                 // blank(c, 64) broadcast
#pragma unroll
    for (int j = 0; j < PF; ++j) {                   // preload diags 0..PF-1
        prb[j]  = Pg[j * U1 + l];
        p64b[j] = Pf[(j * U1 + 64) * 2];
    }

    int d = 1;                                       // current output diagonal
#pragma unroll 1
    for (int blk = 0; blk < NDIAG / PF; ++blk) {
#pragma unroll
        for (int j = 0; j < PF; ++j, ++d) {
            const int c = blk * PF + j;              // consumed diagonal d-1
            const float2 pr  = prb[j];
            const float pb64 = p64b[j];
            const int cn = c + PF;                   // refill slot j
            if (cn < NDIAG) {
                prb[j]  = Pg[cn * U1 + l];
                p64b[j] = Pf[(cn * U1 + 64) * 2];
            }
            float edl = __shfl_up(pr.y, 1, 64);      // emit(c, l-1)
            float al  = __shfl_up(aprev, 1, 64);     // alpha[t, l-1]
            const int t = d - l;
            // primary cell (t, u=l):  logaddexp in log1p form (1 exp, 1 log)
            float va = (t >= 1) ? aprev + pr.x : NEG;
            float vb = (l >= 1) ? al + edl : NEG;
            float mm = fmaxf(va, vb);
            float lo = fminf(va, vb);
            float r  = mm + __logf(1.f + __expf(lo - mm));
            r = (t >= 0 && t < TT) ? r : NEG;
            // secondary cell (t64, u=64) — meaningful on lane 63 only
            const int t64 = d - 64;
            float va64 = (t64 >= 1) ? aprev64 + pb64 : NEG;
            float vb64 = aprev + pr.y;               // alpha(t64,63)+emit(t64,63)
            float mm64 = fmaxf(va64, vb64);
            float lo64 = fminf(va64, vb64);
            float r64  = mm64 + __logf(1.f + __expf(lo64 - mm64));
            r64 = (t64 >= 0) ? r64 : NEG;
            if (d == tl + ul) {
                if (ul < 64) { if (l == ul) res = r; }
                else if (l == 63) res = r64;
            }
            aprev = r; aprev64 = r64;
        }
    }

    const float rr = __shfl(res, (ul < 64) ? ul : 63, 64);
    if (l == 0) out[b] = -(rr + Pg[(tl + ul) * U1 + ul].x);
}

extern "C" void kernel_launch(void* const* d_in, const int* in_sizes, int n_in,
                              void* d_out, int out_size, void* d_ws, size_t ws_size,
                              hipStream_t stream) {
    const float* logits         = (const float*)d_in[0];
    const int*   targets        = (const int*)d_in[1];
    const int*   logit_lengths  = (const int*)d_in[2];
    const int*   target_lengths = (const int*)d_in[3];
    float* outp = (float*)d_out;

    float2* P = (float2*)d_ws;                       // B * DSZ float2 (~800 KB)

    rnnt_lse_kernel<<<NROWS / 4, 256, 0, stream>>>(logits, targets, P);
    rnnt_dp_kernel<<<BB, 64, 0, stream>>>(P, logit_lengths, target_lengths, outp);
}

// Round 3
// 397.459 us; speedup vs baseline: 1.0911x; 1.0826x over previous
//
#include <hip/hip_runtime.h>
#include <hip/hip_bf16.h>

// Problem constants (from reference): B=8, T=128, U=64, V=1024, blank=V-1.
#define BB 8
#define TT 128
#define UU 64
#define VV 1024
#define U1 65                      // U+1
#define NROWS (BB * TT * U1)       // 66560 log-softmax rows
#define NDIAG (TT + UU)            // 192 anti-diagonals
#define DSZ (NDIAG * U1)           // 12480 float2 slots per batch (diag-major)

// Native clang vector type: __builtin_nontemporal_load requires scalar or
// native-vector pointee (HIP_vector_type<float,4> is a struct and is rejected).
typedef float fx4 __attribute__((ext_vector_type(4)));

__device__ __forceinline__ float wave_max64(float v) {
#pragma unroll
    for (int off = 32; off; off >>= 1) v = fmaxf(v, __shfl_xor(v, off, 64));
    return v;
}
__device__ __forceinline__ float wave_sum64(float v) {
#pragma unroll
    for (int off = 32; off; off >>= 1) v += __shfl_xor(v, off, 64);
    return v;
}

// Whole-wave shift-up-by-1 as a single VALU op (DPP wave_shr:1, gfx9 lineage).
// Exactly matches __shfl_up(x,1,64): lane 0 keeps its own value (old=src,
// bound_ctrl=false). Replaces a ~100-cycle ds_bpermute on the DP serial chain
// with a ~4-cycle v_mov_b32_dpp.
__device__ __forceinline__ float shflup1_dpp(float x) {
    int xi = __float_as_int(x);
    int r = __builtin_amdgcn_update_dpp(xi, xi, 0x138 /*wave_shr:1*/, 0xF, 0xF, false);
    return __int_as_float(r);
}

// Kernel 1: one wave per (b,t,u) row of V=1024 logits. Computes logsumexp,
// then extracts the two surviving log-probs (blank=last class, target) from
// the already-loaded registers via shuffles, and writes ONE float2 into the
// diagonal-major slab P[b][(t+u)*U1 + u] = {lp_blank, lp_emit}.
// Logit loads are non-temporal: 272 MB streamed exactly once, keep L2/L3 for P.
__global__ __launch_bounds__(256) void rnnt_lse_kernel(
    const float* __restrict__ logits, const int* __restrict__ targets,
    float2* __restrict__ P) {
    const int wave = threadIdx.x >> 6;
    const int lane = threadIdx.x & 63;
    const int row  = blockIdx.x * 4 + wave;          // grid*4 == NROWS exactly
    const fx4* p4 = (const fx4*)(logits + (size_t)row * VV);

    fx4 x0 = __builtin_nontemporal_load(p4 + lane);
    fx4 x1 = __builtin_nontemporal_load(p4 + lane + 64);
    fx4 x2 = __builtin_nontemporal_load(p4 + lane + 128);
    fx4 x3 = __builtin_nontemporal_load(p4 + lane + 192);

    float m = fmaxf(fmaxf(fmaxf(x0.x, x0.y), fmaxf(x0.z, x0.w)),
                    fmaxf(fmaxf(x1.x, x1.y), fmaxf(x1.z, x1.w)));
    m = fmaxf(m, fmaxf(fmaxf(fmaxf(x2.x, x2.y), fmaxf(x2.z, x2.w)),
                       fmaxf(fmaxf(x3.x, x3.y), fmaxf(x3.z, x3.w))));
    m = wave_max64(m);

    float s = __expf(x0.x - m) + __expf(x0.y - m) + __expf(x0.z - m) + __expf(x0.w - m)
            + __expf(x1.x - m) + __expf(x1.y - m) + __expf(x1.z - m) + __expf(x1.w - m)
            + __expf(x2.x - m) + __expf(x2.y - m) + __expf(x2.z - m) + __expf(x2.w - m)
            + __expf(x3.x - m) + __expf(x3.y - m) + __expf(x3.z - m) + __expf(x3.w - m);
    s = wave_sum64(s);
    const float lse = m + __logf(s);                 // all lanes hold it

    const int b   = row / (TT * U1);
    const int rem = row - b * (TT * U1);
    const int t   = rem / U1;
    const int u   = rem - t * U1;

    // blank logit = element 1023 = x3.w of lane 63
    const float blankv = __shfl(x3.w, 63, 64) - lse;
    float emitv = 0.f;
    if (u < UU) {                                    // wave-uniform branch
        const int tgt = targets[b * UU + u];         // wave-uniform scalar
        const int q = tgt >> 2, grp = q >> 6, sl = q & 63, c = tgt & 3;
        fx4 g4 = (grp == 0) ? x0 : (grp == 1) ? x1 : (grp == 2) ? x2 : x3;
        float cv = (c == 0) ? g4.x : (c == 1) ? g4.y : (c == 2) ? g4.z : g4.w;
        emitv = __shfl(cv, sl, 64) - lse;
    }
    if (lane == 0) P[(size_t)b * DSZ + (t + u) * U1 + u] = make_float2(blankv, emitv);
}

// Kernel 2: anti-diagonal wavefront DP, ONE wave per batch, barrier-free,
// NO LDS. Lane l owns column u=l; lane 63 also owns u=64. alpha diagonal
// lives in registers; neighbor alpha via DPP wave_shr (VALU, not LDS pipe).
// {blank,emit} pairs stream straight into a 16-deep rotating register
// prefetch pipeline (statically indexed via full unroll). Early-exits once
// the block's terminal diagonal d = tl+ul has been computed (avg ~143/192).
#define PF 16                      // prefetch depth; NDIAG/PF = 12 exactly
__global__ __launch_bounds__(64) void rnnt_dp_kernel(
    const float2* __restrict__ P, const int* __restrict__ logit_lengths,
    const int* __restrict__ target_lengths, float* __restrict__ out) {
    const int b = blockIdx.x;
    const int l = threadIdx.x;                       // 0..63
    const float2* Pg = P + (size_t)b * DSZ;
    const float*  Pf = (const float*)Pg;
    const int tl = logit_lengths[b] - 1;             // in [63,127]
    const int ul = target_lengths[b];                // in [32,64]
    const int dend = tl + ul;                        // terminal diagonal, <=191

    const float NEG = -1e30f;
    float aprev   = (l == 0) ? 0.f : NEG;            // diag 0: alpha[0][0]=0
    float aprev64 = NEG;                             // lane63's u=64 cell
    float res = 0.f;

    float2 prb[PF];                                  // {blank(c,l), emit(c,l)}
    float  p64b[PF];                                 // blank(c, 64) broadcast
#pragma unroll
    for (int j = 0; j < PF; ++j) {                   // preload diags 0..PF-1
        prb[j]  = Pg[j * U1 + l];
        p64b[j] = Pf[(j * U1 + 64) * 2];
    }

    int d = 1;                                       // current output diagonal
#pragma unroll 1
    for (int blk = 0; blk < NDIAG / PF; ++blk) {
#pragma unroll
        for (int j = 0; j < PF; ++j, ++d) {
            const int c = blk * PF + j;              // consumed diagonal d-1
            const float2 pr  = prb[j];
            const float pb64 = p64b[j];
            const int cn = c + PF;                   // refill slot j
            if (cn < NDIAG) {
                prb[j]  = Pg[cn * U1 + l];
                p64b[j] = Pf[(cn * U1 + 64) * 2];
            }
            float edl = shflup1_dpp(pr.y);           // emit(c, l-1)
            float al  = shflup1_dpp(aprev);          // alpha[t, l-1]
            const int t = d - l;
            // primary cell (t, u=l):  logaddexp in log1p form (1 exp, 1 log)
            float va = (t >= 1) ? aprev + pr.x : NEG;
            float vb = (l >= 1) ? al + edl : NEG;
            float mm = fmaxf(va, vb);
            float lo = fminf(va, vb);
            float r  = mm + __logf(1.f + __expf(lo - mm));
            r = (t >= 0 && t < TT) ? r : NEG;
            // secondary cell (t64, u=64) — meaningful on lane 63 only
            const int t64 = d - 64;
            float va64 = (t64 >= 1) ? aprev64 + pb64 : NEG;
            float vb64 = aprev + pr.y;               // alpha(t64,63)+emit(t64,63)
            float mm64 = fmaxf(va64, vb64);
            float lo64 = fminf(va64, vb64);
            float r64  = mm64 + __logf(1.f + __expf(lo64 - mm64));
            r64 = (t64 >= 0) ? r64 : NEG;
            if (d == dend) {
                if (ul < 64) { if (l == ul) res = r; }
                else if (l == 63) res = r64;
            }
            aprev = r; aprev64 = r64;
        }
        if (d > dend) break;                         // terminal diag done
    }

    const float rr = __shfl(res, (ul < 64) ? ul : 63, 64);
    if (l == 0) out[b] = -(rr + Pg[(tl + ul) * U1 + ul].x);
}

extern "C" void kernel_launch(void* const* d_in, const int* in_sizes, int n_in,
                              void* d_out, int out_size, void* d_ws, size_t ws_size,
                              hipStream_t stream) {
    const float* logits         = (const float*)d_in[0];
    const int*   targets        = (const int*)d_in[1];
    const int*   logit_lengths  = (const int*)d_in[2];
    const int*   target_lengths = (const int*)d_in[3];
    float* outp = (float*)d_out;

    float2* P = (float2*)d_ws;                       // B * DSZ float2 (~800 KB)

    rnnt_lse_kernel<<<NROWS / 4, 256, 0, stream>>>(logits, targets, P);
    rnnt_dp_kernel<<<BB, 64, 0, stream>>>(P, logit_lengths, target_lengths, outp);
}